// Round 1
// baseline (26037.766 us; speedup 1.0000x reference)
//
#include <hip/hip_runtime.h>
#include <math.h>

#define QQ 512
#define NN 1000
#define HHID 1024
#define CCON 128
#define G4 4000

__device__ inline float wred_min(float v){ for(int o=32;o;o>>=1) v=fminf(v,__shfl_xor(v,o)); return v; }
__device__ inline float wred_max(float v){ for(int o=32;o;o>>=1) v=fmaxf(v,__shfl_xor(v,o)); return v; }
__device__ inline float wred_sum(float v){ for(int o=32;o;o>>=1) v+=__shfl_xor(v,o); return v; }

// C[M,R] = A[M,K] @ B[R,K]^T + bias1[r] + bias2[r]
__global__ __launch_bounds__(256) void gemm_nt(
    const float* __restrict__ A, const float* __restrict__ B,
    const float* __restrict__ bias1, const float* __restrict__ bias2,
    float* __restrict__ C, int M, int K, int R) {
  __shared__ float As[16][65];
  __shared__ float Bs[16][65];
  int tid = threadIdx.x;
  int tx = tid & 15, ty = tid >> 4;
  int m0 = blockIdx.y * 64, r0 = blockIdx.x * 64;
  float acc[4][4] = {};
  for (int k0 = 0; k0 < K; k0 += 16) {
#pragma unroll
    for (int i = 0; i < 4; i++) {
      int idx = tid + 256 * i;
      int ml = idx >> 4, kl = idx & 15;
      int m = m0 + ml, k = k0 + kl;
      As[kl][ml] = (m < M && k < K) ? A[(size_t)m * K + k] : 0.f;
      int r = r0 + ml;
      Bs[kl][ml] = (r < R && k < K) ? B[(size_t)r * K + k] : 0.f;
    }
    __syncthreads();
#pragma unroll
    for (int kk = 0; kk < 16; kk++) {
      float a[4], b[4];
#pragma unroll
      for (int i = 0; i < 4; i++) a[i] = As[kk][ty * 4 + i];
#pragma unroll
      for (int j = 0; j < 4; j++) b[j] = Bs[kk][tx * 4 + j];
#pragma unroll
      for (int i = 0; i < 4; i++)
#pragma unroll
        for (int j = 0; j < 4; j++) acc[i][j] += a[i] * b[j];
    }
    __syncthreads();
  }
#pragma unroll
  for (int i = 0; i < 4; i++) {
    int m = m0 + ty * 4 + i;
    if (m >= M) continue;
#pragma unroll
    for (int j = 0; j < 4; j++) {
      int r = r0 + tx * 4 + j;
      if (r >= R) continue;
      float v = acc[i][j];
      if (bias1) v += bias1[r];
      if (bias2) v += bias2[r];
      C[(size_t)m * R + r] = v;
    }
  }
}

// One LSTM timestep for one layer.
// gates[r] = P[t][r] + sum_k Whh[r][k] * h[t-1][k];  r = q*1000 + n
// 250 blocks x 256 threads; wave w of block b owns output n = b*4+w.
__global__ __launch_bounds__(256) void lstm_step(
    const float* __restrict__ P,    // [QQ, G4] input-side gates (bias included)
    const float* __restrict__ Whh,  // [G4, NN]
    float* __restrict__ Hall,       // [QQ, NN] this layer's h trajectory
    float* __restrict__ cbuf,       // [NN]
    int t) {
  __shared__ float hs[NN];
  int tid = threadIdx.x;
  if (t > 0) {
    for (int i = tid; i < NN; i += 256) hs[i] = Hall[(size_t)(t - 1) * NN + i];
  }
  __syncthreads();
  int wave = tid >> 6, lane = tid & 63;
  int n = blockIdx.x * 4 + wave;
  float g[4];
#pragma unroll
  for (int q = 0; q < 4; q++) {
    int r = q * NN + n;
    float acc = 0.f;
    if (t > 0) {
      const float* wrow = Whh + (size_t)r * NN;
#pragma unroll
      for (int it = 0; it < 16; it++) {
        int k = lane + 64 * it;
        if (k < NN) acc += wrow[k] * hs[k];
      }
    }
#pragma unroll
    for (int o = 32; o; o >>= 1) acc += __shfl_xor(acc, o);
    g[q] = acc + P[(size_t)t * G4 + r];
  }
  if (lane == 0) {
    float cprev = (t > 0) ? cbuf[n] : 0.f;
    float ii = 1.f / (1.f + expf(-g[0]));
    float ff = 1.f / (1.f + expf(-g[1]));
    float gg = tanhf(g[2]);
    float oo = 1.f / (1.f + expf(-g[3]));
    float c = ff * cprev + ii * gg;
    float h = oo * tanhf(c);
    cbuf[n] = c;
    Hall[(size_t)t * NN + n] = h;
  }
}

// Per-timestep output: min/max normalize + floored exp IRF. One block per t.
__global__ __launch_bounds__(256) void epilogue_out(
    const float* __restrict__ H7,   // [QQ, NN]
    const float* __restrict__ Wlin, const float* __restrict__ blin,
    const int* __restrict__ ccol, const float* __restrict__ Dnz,
    float* __restrict__ out,        // [QQ, NN]
    float* __restrict__ irbuf, float* __restrict__ mnirbuf) {
  int t = blockIdx.x, tid = threadIdx.x;
  int wave = tid >> 6, lane = tid & 63;
  __shared__ float hbuf[NN];
  __shared__ float smin[4], smax[4];
  __shared__ float bc[2];
  float lmin = 3.4e38f, lmax = -3.4e38f;
  for (int i = tid; i < NN; i += 256) {
    float v = H7[(size_t)t * NN + i];
    hbuf[i] = v;
    lmin = fminf(lmin, v); lmax = fmaxf(lmax, v);
  }
  lmin = wred_min(lmin); lmax = wred_max(lmax);
  if (lane == 0) { smin[wave] = lmin; smax[wave] = lmax; }
  __syncthreads();
  if (tid == 0) {
    bc[0] = fminf(fminf(smin[0], smin[1]), fminf(smin[2], smin[3]));
    bc[1] = fmaxf(fmaxf(smax[0], smax[1]), fmaxf(smax[2], smax[3]));
  }
  __syncthreads();
  float hmn = bc[0], hmx = bc[1];
  float clo = 3.4e38f, chi = -3.4e38f;
  if (tid < CCON) {
    float w = Wlin[tid], b = blin[tid];
    clo = b + fminf(w * hmn, w * hmx);
    chi = b + fmaxf(w * hmn, w * hmx);
  }
  clo = wred_min(clo); chi = wred_max(chi);
  __syncthreads();  // smin/smax reused below
  if (lane == 0) { smin[wave] = clo; smax[wave] = chi; }
  __syncthreads();
  if (tid == 0) {
    float mn = fminf(fminf(smin[0], smin[1]), fminf(smin[2], smin[3]));
    float mx = fmaxf(fmaxf(smax[0], smax[1]), fmaxf(smax[2], smax[3]));
    float ir = 1.f / (mx - mn);
    bc[0] = mn; bc[1] = ir;
    irbuf[t] = ir;
    mnirbuf[t] = mn * ir;
  }
  __syncthreads();
  float mn = bc[0], ir = bc[1];
  int cc = ccol[t];
  float wcc = Wlin[cc], bcc = blin[cc], d = Dnz[t];
  for (int n = tid; n < NN; n += 256) {
    float s = (hbuf[n] * wcc + bcc - mn) * ir;
    out[(size_t)t * NN + n] = fmaxf(0.25f, 1.f - expf(-10.f * (s - d)));
  }
}

__global__ void reduce_scalars(const float* __restrict__ ir,
                               const float* __restrict__ mnir,
                               float* __restrict__ scal) {
  int tid = threadIdx.x;  // 512
  int wave = tid >> 6, lane = tid & 63;
  __shared__ float s1[8], s2[8];
  float a = ir[tid], b = mnir[tid];
  a = wred_sum(a); b = wred_sum(b);
  if (lane == 0) { s1[wave] = a; s2[wave] = b; }
  __syncthreads();
  if (tid == 0) {
    float A = 0.f, B = 0.f;
    for (int i = 0; i < 8; i++) { A += s1[i]; B += s2[i]; }
    scal[0] = A; scal[1] = B;
  }
}

__global__ void accum_A(const float* __restrict__ H7,
                        const float* __restrict__ ir,
                        float* __restrict__ Avec) {
  int n = blockIdx.x * 256 + threadIdx.x;
  if (n < NN) {
    float acc = 0.f;
    for (int t = 0; t < QQ; t++) acc += H7[(size_t)t * NN + n] * ir[t];
    Avec[n] = acc;
  }
}

__global__ void skills_out(const float* __restrict__ Avec,
                           const float* __restrict__ Wlin,
                           const float* __restrict__ blin,
                           const float* __restrict__ scal,
                           float* __restrict__ out) {  // [NN, CCON]
  int idx = blockIdx.x * 256 + threadIdx.x;
  if (idx < NN * CCON) {
    int n = idx >> 7, c = idx & 127;
    out[idx] = (Wlin[c] * Avec[n] + blin[c] * scal[0] - scal[1]) * (1.f / (float)QQ);
  }
}

extern "C" void kernel_launch(void* const* d_in, const int* in_sizes, int n_in,
                              void* d_out, int out_size, void* d_ws, size_t ws_size,
                              hipStream_t stream) {
  const float* inputs = (const float*)d_in[0];
  const int*   ccol   = (const int*)d_in[1];
  const float* W_inp  = (const float*)d_in[2];
  const float* b_inp  = (const float*)d_in[3];
  const float* W_ih0  = (const float*)d_in[4];
  const float* W_hh0  = (const float*)d_in[5];
  const float* b_ih0  = (const float*)d_in[6];
  const float* b_hh0  = (const float*)d_in[7];
  const float* W_ih   = (const float*)d_in[8];   // [7, 4000, 1000]
  const float* W_hh   = (const float*)d_in[9];   // [7, 4000, 1000]
  const float* b_ih   = (const float*)d_in[10];  // [7, 4000]
  const float* b_hh   = (const float*)d_in[11];  // [7, 4000]
  const float* W_lin  = (const float*)d_in[12];  // [128]
  const float* b_lin  = (const float*)d_in[13];  // [128]
  const float* D_nz   = (const float*)d_in[14];  // [512]

  float* ws = (float*)d_ws;
  float* X    = ws;                       // [512,1024]
  float* P    = X + (size_t)QQ * HHID;    // [512,4000]
  float* H0   = P + (size_t)QQ * G4;      // [512,1000]
  float* H1   = H0 + (size_t)QQ * NN;     // [512,1000]
  float* cbuf = H1 + (size_t)QQ * NN;     // [1024]
  float* irb  = cbuf + 1024;              // [512]
  float* mnir = irb + QQ;                 // [512]
  float* Avec = mnir + QQ;                // [1024]
  float* scal = Avec + 1024;              // [2]

  float* out_main   = (float*)d_out;            // [512,1000]
  float* out_skills = (float*)d_out + QQ * NN;  // [1000,128]

  // X = inputs @ W_inp^T + b_inp   (M=512, K=1000, R=1024)
  gemm_nt<<<dim3(HHID / 64, QQ / 64), 256, 0, stream>>>(
      inputs, W_inp, b_inp, nullptr, X, QQ, NN, HHID);
  // P0 = X @ W_ih0^T + b_ih0 + b_hh0   (M=512, K=1024, R=4000)
  gemm_nt<<<dim3((G4 + 63) / 64, QQ / 64), 256, 0, stream>>>(
      X, W_ih0, b_ih0, b_hh0, P, QQ, HHID, G4);
  for (int t = 0; t < QQ; t++)
    lstm_step<<<250, 256, 0, stream>>>(P, W_hh0, H0, cbuf, t);

  for (int l = 1; l < 8; l++) {
    float* Hprev = ((l - 1) & 1) ? H1 : H0;
    float* Hcur  = (l & 1) ? H1 : H0;
    const float* wih = W_ih + (size_t)(l - 1) * G4 * NN;
    const float* whh = W_hh + (size_t)(l - 1) * G4 * NN;
    gemm_nt<<<dim3((G4 + 63) / 64, QQ / 64), 256, 0, stream>>>(
        Hprev, wih, b_ih + (size_t)(l - 1) * G4, b_hh + (size_t)(l - 1) * G4,
        P, QQ, NN, G4);
    for (int t = 0; t < QQ; t++)
      lstm_step<<<250, 256, 0, stream>>>(P, whh, Hcur, cbuf, t);
  }
  float* H7 = H1;  // layer 7 writes H1

  epilogue_out<<<QQ, 256, 0, stream>>>(H7, W_lin, b_lin, ccol, D_nz,
                                       out_main, irb, mnir);
  reduce_scalars<<<1, 512, 0, stream>>>(irb, mnir, scal);
  accum_A<<<4, 256, 0, stream>>>(H7, irb, Avec);
  skills_out<<<(NN * CCON) / 256, 256, 0, stream>>>(Avec, W_lin, b_lin, scal,
                                                    out_skills);
}